// Round 10
// baseline (132.656 us; speedup 1.0000x reference)
//
#include <hip/hip_runtime.h>

// LevelLayer fully fused, one persistent kernel, 512 blocks x 512 thr.
// ROUND 10: critical-path surgery (no numeric changes vs round 9).
//  - kNN results stay in REGISTERS: wave wv owns nodes {2wv, 2wv+1} in both
//    kNN and the GIN gather; neighbor ids travel via one __shfl(pack, k)
//    (pack = myj0 | myj1<<16 on lanes 0..14). Deletes the snb LDS array,
//    its stores, and the kNN->GIN1 __syncthreads -- each wave starts its
//    gather as soon as its own kNN finishes.
//  - GIN phase-2 weight fragments are preloaded BEFORE the event barriers:
//    their L2 latency is absorbed into the barrier's vmcnt(0) wait, so the
//    post-barrier MFMAs fire without a cold-load stall.
//  - pos staging reverted to contiguous AoS loads (round 9's SoA was
//    3-way strided globally; AoS reads in LDS are 2-way = free).
// Structure: event-local 16-arrival barriers, agent-scope coherence stores,
// MFMA for all 64/128-wide matmuls, exact fp32 pos chain for kNN inputs.
// Outputs in d_out: h[8192*64] | x_emb[8192*4] | ei[2*122880].

#define N_NODES 8192
#define NPE     256
#define KNN     15
#define LAT     64
#define HID     128
#define NK      (N_NODES*KNN)
#define NBLK    512
#define NTHR    512
#define NPB     16
#define NEV     32
#define BPEV    16
#define EI0     (N_NODES*LAT + N_NODES*4)
#define PADM    68
#define PADH    68
#define PADT    136

#define BARA_CNT 0              // + ev*128
#define BARA_FLG 4096
#define BARB_CNT 8192
#define BARB_FLG 12288
#define BAR_BYTES 16384

#define OFF_HA  BAR_BYTES
#define OFF_HB  (OFF_HA + N_NODES*LAT*4)
#define OFF_POS (OFF_HB + N_NODES*LAT*4)

typedef unsigned short bf16;
typedef unsigned int   u32;
typedef unsigned long long u64;
typedef short s16x8 __attribute__((ext_vector_type(8)));
typedef float f32x4 __attribute__((ext_vector_type(4)));

__device__ __forceinline__ float bf2f(bf16 s) {
    union { u32 u; float f; } v; v.u = ((u32)s) << 16; return v.f;
}
__device__ __forceinline__ bf16 f2bf(float f) {
    union { float f; u32 u; } v; v.f = f;
    u32 u = v.u + 0x7fffu + ((v.u >> 16) & 1u);   // RNE
    return (bf16)(u >> 16);
}
__device__ __forceinline__ float ldf(const void* p, int i, int f32) {
    return f32 ? ((const float*)p)[i] : bf2f(((const bf16*)p)[i]);
}
__device__ __forceinline__ void st_coh(float* p, float v) {
    __hip_atomic_store(p, v, __ATOMIC_RELAXED, __HIP_MEMORY_SCOPE_AGENT);
}

// ---- MFMA fragment helpers --------------------------------------------------
union Frag { u32 w[4]; s16x8 v; };

__device__ __forceinline__ u32 cvtpk(float a, float b) {
    u32 r; asm("v_cvt_pk_bf16_f32 %0, %1, %2" : "=v"(r) : "v"(a), "v"(b));
    return r;
}
__device__ __forceinline__ float lo2f(u32 w) { union {u32 u; float f;} v; v.u = w << 16;         return v.f; }
__device__ __forceinline__ float hi2f(u32 w) { union {u32 u; float f;} v; v.u = w & 0xffff0000u; return v.f; }

__device__ __forceinline__ void split8(const float* x, Frag& hi, Frag& lo) {
    #pragma unroll
    for (int i = 0; i < 4; i++) {
        hi.w[i] = cvtpk(x[2*i], x[2*i+1]);
        lo.w[i] = cvtpk(x[2*i]   - lo2f(hi.w[i]),
                        x[2*i+1] - hi2f(hi.w[i]));
    }
}
__device__ __forceinline__ void packA(const float* p, Frag& hi, Frag& lo) {
    float xv[8];
    *(float4*)&xv[0] = *(const float4*)p;
    *(float4*)&xv[4] = *(const float4*)(p + 4);
    split8(xv, hi, lo);
}
__device__ __forceinline__ void loadB_bf(const bf16* p, int stride, Frag& f) {
    #pragma unroll
    for (int i = 0; i < 4; i++)
        f.w[i] = (u32)p[(2*i)*stride] | ((u32)p[(2*i+1)*stride] << 16);
}
__device__ __forceinline__ void loadB_f32(const float* p, int stride, Frag& hi, Frag& lo) {
    float xv[8];
    #pragma unroll
    for (int j = 0; j < 8; j++) xv[j] = p[j*stride];
    split8(xv, hi, lo);
}
__device__ __forceinline__ f32x4 MF(const Frag& a, const Frag& b, f32x4 c) {
    return __builtin_amdgcn_mfma_f32_16x16x32_bf16(a.v, b.v, c, 0, 0, 0);
}
// preload one 16-wide N-tile of Wa (K=64, two K-steps) + bias
__device__ __forceinline__ void preWa(const void* Wa, const void* ba, int f32,
        int ncols, int u0, int ln15, int kg,
        Frag& b0h, Frag& b0l, Frag& b1h, Frag& b1l, float& bias)
{
    bias = ldf(ba, u0 + ln15, f32);
    if (f32) {
        const float* W = (const float*)Wa;
        loadB_f32(W + ( 0 + kg*8)*ncols + u0 + ln15, ncols, b0h, b0l);
        loadB_f32(W + (32 + kg*8)*ncols + u0 + ln15, ncols, b1h, b1l);
    } else {
        const bf16* W = (const bf16*)Wa;
        loadB_bf(W + ( 0 + kg*8)*ncols + u0 + ln15, ncols, b0h);
        loadB_bf(W + (32 + kg*8)*ncols + u0 + ln15, ncols, b1h);
    }
}

struct KArgs {
    const void* x;
    const void* se1; const void* bse1; const void* se2; const void* bse2;
    const void* g1a; const void* bg1a; const void* g1b; const void* bg1b;
    const void* g2a; const void* bg2a; const void* g2b; const void* bg2b;
    const void* oe1; const void* boe1; const void* oe2; const void* boe2;
    const u32* wdet;
    float* hA; float* hB; float* pos; int* bar;
    void* out;
};

struct Shm {
    union {
        int   red[8];                                      // detect wave partials
        float hid[NPB][PADH];                              // space mid
        float kp[NPE*3];                                   // knn pos AoS
        float st[NPB*LAT];                                 // out mid
    } u;
    float m[NPB*PADM];
    float own[NPB*LAT];
    struct { bf16 hi[NPB*PADT]; bf16 lo[NPB*PADT]; } t;
    float sh[NPB*PADH];
    int   flag;
};                                                         // ~26 KB

// Fence-free per-event barrier (16 arrivals). Bounded spin.
__device__ __forceinline__ void eventbar(int* cnt, int* flg) {
    asm volatile("s_waitcnt vmcnt(0)" ::: "memory");
    __syncthreads();
    if (threadIdx.x == 0) {
        if (__hip_atomic_fetch_add(cnt, 1, __ATOMIC_RELAXED,
                                   __HIP_MEMORY_SCOPE_AGENT) == BPEV - 1) {
            __hip_atomic_store(flg, 1, __ATOMIC_RELAXED,
                               __HIP_MEMORY_SCOPE_AGENT);
        }
        int guard = 0;
        while (__hip_atomic_load(flg, __ATOMIC_RELAXED,
                                 __HIP_MEMORY_SCOPE_AGENT) == 0) {
            __builtin_amdgcn_s_sleep(1);
            if (++guard > (1 << 21)) break;
        }
        __builtin_amdgcn_fence(__ATOMIC_ACQUIRE, "workgroup");
    }
    __syncthreads();
}

// GIN layer via MFMA. Neighbor ids arrive via __shfl from registers (mypack);
// phase-2 weight fragments arrive preloaded (issued before the barrier).
template<bool LAST>
__device__ __forceinline__ void gin_layer(Shm& S, int base, int eb, int f32,
        u32 mypack,
        const float* __restrict__ hin, float* hout,
        const Frag& pb0h, const Frag& pb0l, const Frag& pb1h, const Frag& pb1l,
        float pbias,
        const void* Wb, const void* bb, void* out)
{
    const int tid = threadIdx.x;
    const int lane = tid & 63, wv = tid >> 6;
    const int ln15 = lane & 15, kg = lane >> 4;

    // ---- gather (wave-local, starts immediately after this wave's kNN):
    // thread = (node n = wv*2 + half, float2 slot sl)
    {
        const int n = tid >> 5, sl = tid & 31, half = (tid >> 5) & 1;
        const float2* h2 = (const float2*)hin;
        const float2 o = h2[(size_t)(base + n)*32 + sl];
        *(float2*)&S.own[n*LAT + sl*2] = o;
        float2 vv[KNN];
        #pragma unroll
        for (int k = 0; k < KNN; k++) {
            const u32 p = __shfl(mypack, k, 64);
            const int nb = eb + (int)((p >> (16*half)) & 0xffffu);
            vv[k] = h2[(size_t)nb*32 + sl];
        }
        float2 mm;
        {
            float s0 = vv[0].x+vv[1].x, s1 = vv[2].x+vv[3].x, s2 = vv[4].x+vv[5].x;
            float s3 = vv[6].x+vv[7].x, s4 = vv[8].x+vv[9].x, s5 = vv[10].x+vv[11].x;
            float s6 = vv[12].x+vv[13].x;
            mm.x = o.x + (((s0+s1)+(s2+s3)) + ((s4+s5)+(s6+vv[14].x)));
        }
        {
            float s0 = vv[0].y+vv[1].y, s1 = vv[2].y+vv[3].y, s2 = vv[4].y+vv[5].y;
            float s3 = vv[6].y+vv[7].y, s4 = vv[8].y+vv[9].y, s5 = vv[10].y+vv[11].y;
            float s6 = vv[12].y+vv[13].y;
            mm.y = o.y + (((s0+s1)+(s2+s3)) + ((s4+s5)+(s6+vv[14].y)));
        }
        *(float2*)&S.m[n*PADM + sl*2] = mm;
        __syncthreads();
    }

    // ---- phase 2 (MFMA): t[16][128] = relu(m @ Wa + ba); 8 waves x N-tile
    {
        const int u0 = wv * 16;
        f32x4 acc; acc[0] = pbias; acc[1] = pbias; acc[2] = pbias; acc[3] = pbias;
        Frag a0h, a0l, a1h, a1l;
        packA(&S.m[ln15*PADM +  0 + kg*8], a0h, a0l);
        packA(&S.m[ln15*PADM + 32 + kg*8], a1h, a1l);
        if (f32) {
            acc = MF(a0h, pb0h, acc); acc = MF(a0l, pb0h, acc); acc = MF(a0h, pb0l, acc);
            acc = MF(a1h, pb1h, acc); acc = MF(a1l, pb1h, acc); acc = MF(a1h, pb1l, acc);
        } else {
            acc = MF(a0h, pb0h, acc); acc = MF(a0l, pb0h, acc);
            acc = MF(a1h, pb1h, acc); acc = MF(a1l, pb1h, acc);
        }
        #pragma unroll
        for (int r = 0; r < 4; r++) {
            const int row = kg*4 + r;
            float v = acc[r]; v = v > 0.f ? v : 0.f;
            const bf16 h = f2bf(v);
            S.t.hi[row*PADT + u0 + ln15] = h;
            S.t.lo[row*PADT + u0 + ln15] = f2bf(v - bf2f(h));
        }
    }
    __syncthreads();

    // ---- phase 3 (MFMA, waves 0-3): g[16][64] = t @ Wb + bb + own
    if (wv < 4) {
        const int f0 = wv * 16;
        const float bias = ldf(bb, f0 + ln15, f32);
        f32x4 acc; acc[0] = bias; acc[1] = bias; acc[2] = bias; acc[3] = bias;
        #pragma unroll
        for (int s = 0; s < 4; s++) {
            Frag ah, al;
            ah.v = *(const s16x8*)&S.t.hi[ln15*PADT + s*32 + kg*8];
            al.v = *(const s16x8*)&S.t.lo[ln15*PADT + s*32 + kg*8];
            if (f32) {
                const float* W = (const float*)Wb;
                Frag bh, bl;
                loadB_f32(W + (s*32 + kg*8)*LAT + f0 + ln15, LAT, bh, bl);
                acc = MF(ah, bh, acc); acc = MF(al, bh, acc); acc = MF(ah, bl, acc);
            } else {
                const bf16* W = (const bf16*)Wb;
                Frag b;
                loadB_bf(W + (s*32 + kg*8)*LAT + f0 + ln15, LAT, b);
                acc = MF(ah, b, acc); acc = MF(al, b, acc);
            }
        }
        #pragma unroll
        for (int r = 0; r < 4; r++) {
            const int row = kg*4 + r, f = f0 + ln15, gi = base + row;
            const float o = acc[r] + S.own[row*LAT + f];
            if (!LAST) {
                st_coh(&hout[gi*LAT + f], o);
            } else {
                S.sh[row*PADH + f] = o;
                if (f32) ((float*)out)[gi*LAT + f] = o;     // output 0: final h
                else     ((bf16*)out)[gi*LAT + f] = f2bf(o);
            }
        }
    }
    __syncthreads();
}

__global__ __launch_bounds__(NTHR, 4) void k_fused(KArgs a)
{
    __shared__ Shm S;
    const int tid = threadIdx.x, blk = blockIdx.x;
    const int lane = tid & 63, wv = tid >> 6;
    const int ln15 = lane & 15, kg = lane >> 4;
    const int ev   = blk & (NEV - 1);
    const int slc  = blk >> 5;
    const int base = ev * NPE + slc * NPB;
    const int eb   = ev * NPE;

    // ---- P0: dtype detect (16 KB scan; wave shfl-reduce)
    {
        int c = 0;
        for (int i = tid; i < 4096; i += NTHR) {
            const u32 x = a.wdet[i];
            c += ((x >> 7)  & 0xffu) >= 0xC8u;
            c += ((x >> 23) & 0xffu) >= 0xC8u;
        }
        #pragma unroll
        for (int s = 32; s >= 1; s >>= 1) c += __shfl_xor(c, s, 64);
        if (lane == 0) S.u.red[wv] = c;
        __syncthreads();
        if (tid == 0) {
            int t = 0;
            #pragma unroll
            for (int i = 0; i < 8; i++) t += S.u.red[i];
            S.flag = (t > 64) ? 1 : 0;
        }
        __syncthreads();
    }
    const int f32 = S.flag;
    __syncthreads();

    // ---- P1: space_emb  h = leaky(x@W1+b1)@W2+b2
    {
        #pragma unroll
        for (int p = 0; p < 2; p++) {
            const int e = tid + p*NTHR, n = e >> 6, f = e & 63, node = base + n;
            float xr[4];
            if (f32) {
                const float4 x4 = ((const float4*)a.x)[node];
                xr[0] = x4.x; xr[1] = x4.y; xr[2] = x4.z; xr[3] = x4.w;
            } else {
                const ushort4 x4 = ((const ushort4*)a.x)[node];
                xr[0] = bf2f(x4.x); xr[1] = bf2f(x4.y);
                xr[2] = bf2f(x4.z); xr[3] = bf2f(x4.w);
            }
            float acc = ldf(a.bse1, f, f32);
            #pragma unroll
            for (int i = 0; i < 4; i++)
                acc = fmaf(xr[i], ldf(a.se1, i*LAT + f, f32), acc);
            acc = acc > 0.f ? acc : 0.01f*acc;              // leaky
            S.u.hid[n][f] = acc;
        }
        __syncthreads();
        // p2a (waves 0-3, MFMA): hA[16][64] = hid @ W2 + b2
        if (wv < 4) {
            const int f0 = wv * 16;
            const float bias = ldf(a.bse2, f0 + ln15, f32);
            f32x4 acc; acc[0] = bias; acc[1] = bias; acc[2] = bias; acc[3] = bias;
            Frag a0h, a0l, a1h, a1l;
            packA(&S.u.hid[ln15][ 0 + kg*8], a0h, a0l);
            packA(&S.u.hid[ln15][32 + kg*8], a1h, a1l);
            if (f32) {
                const float* W = (const float*)a.se2;
                Frag b0h, b0l, b1h, b1l;
                loadB_f32(W + ( 0 + kg*8)*LAT + f0 + ln15, LAT, b0h, b0l);
                loadB_f32(W + (32 + kg*8)*LAT + f0 + ln15, LAT, b1h, b1l);
                acc = MF(a0h, b0h, acc); acc = MF(a0l, b0h, acc); acc = MF(a0h, b0l, acc);
                acc = MF(a1h, b1h, acc); acc = MF(a1l, b1h, acc); acc = MF(a1h, b1l, acc);
            } else {
                const bf16* W = (const bf16*)a.se2;
                Frag b0, b1;
                loadB_bf(W + ( 0 + kg*8)*LAT + f0 + ln15, LAT, b0);
                loadB_bf(W + (32 + kg*8)*LAT + f0 + ln15, LAT, b1);
                acc = MF(a0h, b0, acc); acc = MF(a0l, b0, acc);
                acc = MF(a1h, b1, acc); acc = MF(a1l, b1, acc);
            }
            #pragma unroll
            for (int r = 0; r < 4; r++) {
                const int row = kg*4 + r;
                st_coh(&a.hA[(base + row)*LAT + f0 + ln15], acc[r]);
            }
        } else if (tid - 256 < 48) {
            // p2b: EXACT pos (3 cols) -- bit-identical fmaf chain (rounds 3-9)
            const int idx = tid - 256, n = idx / 3, f = idx % 3;
            float acc = ldf(a.bse2, f, f32);
            if (f32) {
                const float* W = (const float*)a.se2;
                #pragma unroll 8
                for (int j = 0; j < LAT; j++)
                    acc = fmaf(S.u.hid[n][j], W[j*LAT + f], acc);
            } else {
                const bf16* W = (const bf16*)a.se2;
                #pragma unroll 8
                for (int j = 0; j < LAT; j++)
                    acc = fmaf(S.u.hid[n][j], bf2f(W[j*LAT + f]), acc);
            }
            st_coh(&a.pos[(base + n)*3 + f], acc);
        }
    }

    // ---- preload GIN1 phase-2 Wa fragments; latency hides under barrier A
    Frag g1b0h, g1b0l, g1b1h, g1b1l; float g1bias;
    preWa(a.g1a, a.bg1a, f32, HID, wv*16, ln15, kg,
          g1b0h, g1b0l, g1b1h, g1b1l, g1bias);
    eventbar(a.bar + (BARA_CNT + ev*128)/4, a.bar + (BARA_FLG + ev*128)/4);

    // ---- P2: kNN; 8 waves x 2 nodes, interleaved butterfly chains.
    u32 mypack;
    {
        for (int i = tid; i < NPE*3; i += NTHR) S.u.kp[i] = a.pos[(size_t)eb*3 + i];
        __syncthreads();
        const int n0 = base + wv*2, n1 = n0 + 1;
        const int nl0 = n0 - eb, nl1 = n1 - eb;
        const float px0 = S.u.kp[nl0*3], py0 = S.u.kp[nl0*3+1], pz0 = S.u.kp[nl0*3+2];
        const float px1 = S.u.kp[nl1*3], py1 = S.u.kp[nl1*3+1], pz1 = S.u.kp[nl1*3+2];
        u64 key0[4], key1[4];
        #pragma unroll
        for (int c = 0; c < 4; c++) {
            const int j = 64*c + lane;
            const float qx = S.u.kp[j*3], qy = S.u.kp[j*3+1], qz = S.u.kp[j*3+2];
            {
                const float dx = px0 - qx, dy = py0 - qy, dz = pz0 - qz;
                float dd = __fmul_rn(dx, dx);
                dd = __fadd_rn(dd, __fmul_rn(dy, dy));
                dd = __fadd_rn(dd, __fmul_rn(dz, dz));
                key0[c] = ((u64)__float_as_uint(dd) << 32) | (u32)j;
                if (j == nl0) key0[c] = ~0ull;
            }
            {
                const float dx = px1 - qx, dy = py1 - qy, dz = pz1 - qz;
                float dd = __fmul_rn(dx, dx);
                dd = __fadd_rn(dd, __fmul_rn(dy, dy));
                dd = __fadd_rn(dd, __fmul_rn(dz, dz));
                key1[c] = ((u64)__float_as_uint(dd) << 32) | (u32)j;
                if (j == nl1) key1[c] = ~0ull;
            }
        }
        #define CSWAP(K,A,B) { const u64 x_ = K[A], y_ = K[B]; \
                               K[A] = x_ < y_ ? x_ : y_; K[B] = x_ < y_ ? y_ : x_; }
        CSWAP(key0,0,1) CSWAP(key0,2,3) CSWAP(key0,0,2) CSWAP(key0,1,3) CSWAP(key0,1,2)
        CSWAP(key1,0,1) CSWAP(key1,2,3) CSWAP(key1,0,2) CSWAP(key1,1,3) CSWAP(key1,1,2)
        #undef CSWAP
        int myj0 = 0, myj1 = 0;
        #pragma unroll
        for (int k = 0; k < KNN; k++) {
            u64 m0 = key0[0], m1 = key1[0];
            #pragma unroll
            for (int s = 32; s >= 1; s >>= 1) {
                const u64 o0 = __shfl_xor(m0, s, 64);
                const u64 o1 = __shfl_xor(m1, s, 64);
                m0 = o0 < m0 ? o0 : m0;
                m1 = o1 < m1 ? o1 : m1;
            }
            if (lane == k) { myj0 = (int)(u32)m0; myj1 = (int)(u32)m1; }
            const bool h0 = (key0[0] == m0);
            key0[0] = h0 ? key0[1] : key0[0];
            key0[1] = h0 ? key0[2] : key0[1];
            key0[2] = h0 ? key0[3] : key0[2];
            key0[3] = h0 ? ~0ull   : key0[3];
            const bool h1 = (key1[0] == m1);
            key1[0] = h1 ? key1[1] : key1[0];
            key1[1] = h1 ? key1[2] : key1[1];
            key1[2] = h1 ? key1[3] : key1[2];
            key1[3] = h1 ? ~0ull   : key1[3];
        }
        mypack = (u32)myj0 | ((u32)myj1 << 16);
        if (lane < KNN) {
            const int gj0 = eb + myj0, gj1 = eb + myj1;
            if (f32) {
                float* o = (float*)a.out;
                o[EI0 + n0*KNN + lane]      = (float)gj0;   // output 2: ei
                o[EI0 + NK + n0*KNN + lane] = (float)n0;
                o[EI0 + n1*KNN + lane]      = (float)gj1;
                o[EI0 + NK + n1*KNN + lane] = (float)n1;
            } else {
                bf16* o = (bf16*)a.out;
                o[EI0 + n0*KNN + lane]      = f2bf((float)gj0);
                o[EI0 + NK + n0*KNN + lane] = f2bf((float)n0);
                o[EI0 + n1*KNN + lane]      = f2bf((float)gj1);
                o[EI0 + NK + n1*KNN + lane] = f2bf((float)n1);
            }
        }
        // no __syncthreads: each wave proceeds straight into its own gather
    }

    // ---- P3: GIN layer 1 (MFMA, hA -> hB)
    gin_layer<false>(S, base, eb, f32, mypack, a.hA, a.hB,
                     g1b0h, g1b0l, g1b1h, g1b1l, g1bias,
                     a.g1b, a.bg1b, nullptr);

    // ---- preload GIN2 phase-2 Wa fragments; latency hides under barrier B
    Frag g2b0h, g2b0l, g2b1h, g2b1l; float g2bias;
    preWa(a.g2a, a.bg2a, f32, HID, wv*16, ln15, kg,
          g2b0h, g2b0l, g2b1h, g2b1l, g2bias);
    eventbar(a.bar + (BARB_CNT + ev*128)/4, a.bar + (BARB_FLG + ev*128)/4);

    // ---- P4: GIN layer 2 (MFMA, hB -> sh + d_out h)
    gin_layer<true>(S, base, eb, f32, mypack, a.hB, nullptr,
                    g2b0h, g2b0l, g2b1h, g2b1l, g2bias,
                    a.g2b, a.bg2b, a.out);

    // ---- P5: out_emb FFN
    {
        // p1 (waves 0-3, MFMA): st[16][64] = leaky(sh @ oe1 + boe1)
        if (wv < 4) {
            const int f0 = wv * 16;
            const float bias = ldf(a.boe1, f0 + ln15, f32);
            f32x4 acc; acc[0] = bias; acc[1] = bias; acc[2] = bias; acc[3] = bias;
            Frag a0h, a0l, a1h, a1l;
            packA(&S.sh[ln15*PADH +  0 + kg*8], a0h, a0l);
            packA(&S.sh[ln15*PADH + 32 + kg*8], a1h, a1l);
            if (f32) {
                const float* W = (const float*)a.oe1;
                Frag b0h, b0l, b1h, b1l;
                loadB_f32(W + ( 0 + kg*8)*LAT + f0 + ln15, LAT, b0h, b0l);
                loadB_f32(W + (32 + kg*8)*LAT + f0 + ln15, LAT, b1h, b1l);
                acc = MF(a0h, b0h, acc); acc = MF(a0l, b0h, acc); acc = MF(a0h, b0l, acc);
                acc = MF(a1h, b1h, acc); acc = MF(a1l, b1h, acc); acc = MF(a1h, b1l, acc);
            } else {
                const bf16* W = (const bf16*)a.oe1;
                Frag b0, b1;
                loadB_bf(W + ( 0 + kg*8)*LAT + f0 + ln15, LAT, b0);
                loadB_bf(W + (32 + kg*8)*LAT + f0 + ln15, LAT, b1);
                acc = MF(a0h, b0, acc); acc = MF(a0l, b0, acc);
                acc = MF(a1h, b1, acc); acc = MF(a1l, b1, acc);
            }
            #pragma unroll
            for (int r = 0; r < 4; r++) {
                const int row = kg*4 + r;
                float v = acc[r];
                v = v > 0.f ? v : 0.01f*v;                  // leaky
                S.u.st[row*LAT + f0 + ln15] = v;
            }
        }
        __syncthreads();
        // p2: x_emb = st @ oe2 + boe2 (64 dots of length 64)
        if (tid < NPB*4) {
            const int n = tid >> 2, ff = tid & 3;
            float acc;
            if (f32) {
                const float* W = (const float*)a.oe2;
                acc = ((const float*)a.boe2)[ff];
                for (int j = 0; j < LAT; j++)
                    acc = fmaf(S.u.st[n*LAT + j], W[j*4 + ff], acc);
            } else {
                const bf16* W = (const bf16*)a.oe2;
                acc = bf2f(((const bf16*)a.boe2)[ff]);
                for (int j = 0; j < LAT; j++)
                    acc = fmaf(S.u.st[n*LAT + j], bf2f(W[j*4 + ff]), acc);
            }
            const int xo = N_NODES*LAT + (base + n)*4 + ff; // output 1: x_emb
            if (f32) ((float*)a.out)[xo] = acc;
            else     ((bf16*)a.out)[xo] = f2bf(acc);
        }
    }
}

extern "C" void kernel_launch(void* const* d_in, const int* in_sizes, int n_in,
                              void* d_out, int out_size, void* d_ws, size_t ws_size,
                              hipStream_t stream)
{
    (void)in_sizes; (void)n_in; (void)out_size; (void)ws_size;
    char* ws = (char*)d_ws;

    KArgs a;
    a.x   = d_in[0];
    a.se1 = d_in[3];  a.bse1 = d_in[4];  a.se2 = d_in[5];  a.bse2 = d_in[6];
    a.g1a = d_in[7];  a.bg1a = d_in[8];  a.g1b = d_in[9];  a.bg1b = d_in[10];
    a.g2a = d_in[11]; a.bg2a = d_in[12]; a.g2b = d_in[13]; a.bg2b = d_in[14];
    a.oe1 = d_in[15]; a.boe1 = d_in[16]; a.oe2 = d_in[17]; a.boe2 = d_in[18];
    a.wdet = (const u32*)d_in[7];
    a.hA  = (float*)(ws + OFF_HA);
    a.hB  = (float*)(ws + OFF_HB);
    a.pos = (float*)(ws + OFF_POS);
    a.bar = (int*)ws;
    a.out = d_out;

    hipMemsetAsync(d_ws, 0, BAR_BYTES, stream);
    k_fused<<<dim3(NBLK), dim3(NTHR), 0, stream>>>(a);
}

// Round 11
// 126.576 us; speedup vs baseline: 1.0480x; 1.0480x over previous
//
#include <hip/hip_runtime.h>

// LevelLayer fully fused, one persistent kernel, 512 blocks x 512 thr.
// ROUND 11: revert round-10's cross-phase weight preload (it SPILLED:
// WRITE_SIZE 7.6->23.7MB = ~16MB scratch traffic, fragments held across the
// register-hungry kNN phase). Weights go back to in-phase loads (round 9,
// 44.5us). KEEP round-10's good parts:
//  - kNN results register-resident: wave wv owns nodes {2wv,2wv+1} in both
//    kNN and the GIN gather; neighbor ids travel via __shfl(pack, k)
//    (pack = myj0 | myj1<<16, lanes 0..14). No snb LDS, no kNN->gather sync.
//  - AoS pos staging (coalesced global, 2-way LDS aliasing = free).
// Structure: event-local 16-arrival barriers, agent-scope coherence stores,
// MFMA for all 64/128-wide matmuls (exact hi/lo bf16 split), exact fp32 pos.
// Outputs in d_out: h[8192*64] | x_emb[8192*4] | ei[2*122880].

#define N_NODES 8192
#define NPE     256
#define KNN     15
#define LAT     64
#define HID     128
#define NK      (N_NODES*KNN)
#define NBLK    512
#define NTHR    512
#define NPB     16
#define NEV     32
#define BPEV    16
#define EI0     (N_NODES*LAT + N_NODES*4)
#define PADM    68
#define PADH    68
#define PADT    136

#define BARA_CNT 0              // + ev*128
#define BARA_FLG 4096
#define BARB_CNT 8192
#define BARB_FLG 12288
#define BAR_BYTES 16384

#define OFF_HA  BAR_BYTES
#define OFF_HB  (OFF_HA + N_NODES*LAT*4)
#define OFF_POS (OFF_HB + N_NODES*LAT*4)

typedef unsigned short bf16;
typedef unsigned int   u32;
typedef unsigned long long u64;
typedef short s16x8 __attribute__((ext_vector_type(8)));
typedef float f32x4 __attribute__((ext_vector_type(4)));

__device__ __forceinline__ float bf2f(bf16 s) {
    union { u32 u; float f; } v; v.u = ((u32)s) << 16; return v.f;
}
__device__ __forceinline__ bf16 f2bf(float f) {
    union { float f; u32 u; } v; v.f = f;
    u32 u = v.u + 0x7fffu + ((v.u >> 16) & 1u);   // RNE
    return (bf16)(u >> 16);
}
__device__ __forceinline__ float ldf(const void* p, int i, int f32) {
    return f32 ? ((const float*)p)[i] : bf2f(((const bf16*)p)[i]);
}
__device__ __forceinline__ void st_coh(float* p, float v) {
    __hip_atomic_store(p, v, __ATOMIC_RELAXED, __HIP_MEMORY_SCOPE_AGENT);
}

// ---- MFMA fragment helpers --------------------------------------------------
union Frag { u32 w[4]; s16x8 v; };

__device__ __forceinline__ u32 cvtpk(float a, float b) {
    u32 r; asm("v_cvt_pk_bf16_f32 %0, %1, %2" : "=v"(r) : "v"(a), "v"(b));
    return r;
}
__device__ __forceinline__ float lo2f(u32 w) { union {u32 u; float f;} v; v.u = w << 16;         return v.f; }
__device__ __forceinline__ float hi2f(u32 w) { union {u32 u; float f;} v; v.u = w & 0xffff0000u; return v.f; }

__device__ __forceinline__ void split8(const float* x, Frag& hi, Frag& lo) {
    #pragma unroll
    for (int i = 0; i < 4; i++) {
        hi.w[i] = cvtpk(x[2*i], x[2*i+1]);
        lo.w[i] = cvtpk(x[2*i]   - lo2f(hi.w[i]),
                        x[2*i+1] - hi2f(hi.w[i]));
    }
}
__device__ __forceinline__ void packA(const float* p, Frag& hi, Frag& lo) {
    float xv[8];
    *(float4*)&xv[0] = *(const float4*)p;
    *(float4*)&xv[4] = *(const float4*)(p + 4);
    split8(xv, hi, lo);
}
__device__ __forceinline__ void loadB_bf(const bf16* p, int stride, Frag& f) {
    #pragma unroll
    for (int i = 0; i < 4; i++)
        f.w[i] = (u32)p[(2*i)*stride] | ((u32)p[(2*i+1)*stride] << 16);
}
__device__ __forceinline__ void loadB_f32(const float* p, int stride, Frag& hi, Frag& lo) {
    float xv[8];
    #pragma unroll
    for (int j = 0; j < 8; j++) xv[j] = p[j*stride];
    split8(xv, hi, lo);
}
__device__ __forceinline__ f32x4 MF(const Frag& a, const Frag& b, f32x4 c) {
    return __builtin_amdgcn_mfma_f32_16x16x32_bf16(a.v, b.v, c, 0, 0, 0);
}

struct KArgs {
    const void* x;
    const void* se1; const void* bse1; const void* se2; const void* bse2;
    const void* g1a; const void* bg1a; const void* g1b; const void* bg1b;
    const void* g2a; const void* bg2a; const void* g2b; const void* bg2b;
    const void* oe1; const void* boe1; const void* oe2; const void* boe2;
    const u32* wdet;
    float* hA; float* hB; float* pos; int* bar;
    void* out;
};

struct Shm {
    union {
        int   red[8];                                      // detect wave partials
        float hid[NPB][PADH];                              // space mid
        float kp[NPE*3];                                   // knn pos AoS
        float st[NPB*LAT];                                 // out mid
    } u;
    float m[NPB*PADM];
    float own[NPB*LAT];
    struct { bf16 hi[NPB*PADT]; bf16 lo[NPB*PADT]; } t;
    float sh[NPB*PADH];
    int   flag;
};                                                         // ~26 KB

// Fence-free per-event barrier (16 arrivals). Bounded spin.
__device__ __forceinline__ void eventbar(int* cnt, int* flg) {
    asm volatile("s_waitcnt vmcnt(0)" ::: "memory");
    __syncthreads();
    if (threadIdx.x == 0) {
        if (__hip_atomic_fetch_add(cnt, 1, __ATOMIC_RELAXED,
                                   __HIP_MEMORY_SCOPE_AGENT) == BPEV - 1) {
            __hip_atomic_store(flg, 1, __ATOMIC_RELAXED,
                               __HIP_MEMORY_SCOPE_AGENT);
        }
        int guard = 0;
        while (__hip_atomic_load(flg, __ATOMIC_RELAXED,
                                 __HIP_MEMORY_SCOPE_AGENT) == 0) {
            __builtin_amdgcn_s_sleep(1);
            if (++guard > (1 << 21)) break;
        }
        __builtin_amdgcn_fence(__ATOMIC_ACQUIRE, "workgroup");
    }
    __syncthreads();
}

// GIN layer via MFMA. Neighbor ids arrive via __shfl from registers (mypack);
// weights loaded in-phase (L2-hot; latency overlaps the gather loads).
template<bool LAST>
__device__ __forceinline__ void gin_layer(Shm& S, int base, int eb, int f32,
        u32 mypack,
        const float* __restrict__ hin, float* hout,
        const void* Wa, const void* ba, const void* Wb, const void* bb,
        void* out)
{
    const int tid = threadIdx.x;
    const int lane = tid & 63, wv = tid >> 6;
    const int ln15 = lane & 15, kg = lane >> 4;

    // ---- gather (wave-local, starts right after this wave's kNN):
    // thread = (node n = wv*2 + half, float2 slot sl)
    {
        const int n = tid >> 5, sl = tid & 31, half = (tid >> 5) & 1;
        const float2* h2 = (const float2*)hin;
        const float2 o = h2[(size_t)(base + n)*32 + sl];
        *(float2*)&S.own[n*LAT + sl*2] = o;
        float2 vv[KNN];
        #pragma unroll
        for (int k = 0; k < KNN; k++) {
            const u32 p = __shfl(mypack, k, 64);
            const int nb = eb + (int)((p >> (16*half)) & 0xffffu);
            vv[k] = h2[(size_t)nb*32 + sl];
        }
        float2 mm;
        {
            float s0 = vv[0].x+vv[1].x, s1 = vv[2].x+vv[3].x, s2 = vv[4].x+vv[5].x;
            float s3 = vv[6].x+vv[7].x, s4 = vv[8].x+vv[9].x, s5 = vv[10].x+vv[11].x;
            float s6 = vv[12].x+vv[13].x;
            mm.x = o.x + (((s0+s1)+(s2+s3)) + ((s4+s5)+(s6+vv[14].x)));
        }
        {
            float s0 = vv[0].y+vv[1].y, s1 = vv[2].y+vv[3].y, s2 = vv[4].y+vv[5].y;
            float s3 = vv[6].y+vv[7].y, s4 = vv[8].y+vv[9].y, s5 = vv[10].y+vv[11].y;
            float s6 = vv[12].y+vv[13].y;
            mm.y = o.y + (((s0+s1)+(s2+s3)) + ((s4+s5)+(s6+vv[14].y)));
        }
        *(float2*)&S.m[n*PADM + sl*2] = mm;
        __syncthreads();
    }

    // ---- phase 2 (MFMA): t[16][128] = relu(m @ Wa + ba); 8 waves x N-tile
    {
        const int u0 = wv * 16;
        const float bias = ldf(ba, u0 + ln15, f32);
        f32x4 acc; acc[0] = bias; acc[1] = bias; acc[2] = bias; acc[3] = bias;
        Frag a0h, a0l, a1h, a1l;
        packA(&S.m[ln15*PADM +  0 + kg*8], a0h, a0l);
        packA(&S.m[ln15*PADM + 32 + kg*8], a1h, a1l);
        if (f32) {
            const float* W = (const float*)Wa;
            Frag b0h, b0l, b1h, b1l;
            loadB_f32(W + ( 0 + kg*8)*HID + u0 + ln15, HID, b0h, b0l);
            loadB_f32(W + (32 + kg*8)*HID + u0 + ln15, HID, b1h, b1l);
            acc = MF(a0h, b0h, acc); acc = MF(a0l, b0h, acc); acc = MF(a0h, b0l, acc);
            acc = MF(a1h, b1h, acc); acc = MF(a1l, b1h, acc); acc = MF(a1h, b1l, acc);
        } else {
            const bf16* W = (const bf16*)Wa;
            Frag b0, b1;
            loadB_bf(W + ( 0 + kg*8)*HID + u0 + ln15, HID, b0);
            loadB_bf(W + (32 + kg*8)*HID + u0 + ln15, HID, b1);
            acc = MF(a0h, b0, acc); acc = MF(a0l, b0, acc);
            acc = MF(a1h, b1, acc); acc = MF(a1l, b1, acc);
        }
        #pragma unroll
        for (int r = 0; r < 4; r++) {
            const int row = kg*4 + r;
            float v = acc[r]; v = v > 0.f ? v : 0.f;
            const bf16 h = f2bf(v);
            S.t.hi[row*PADT + u0 + ln15] = h;
            S.t.lo[row*PADT + u0 + ln15] = f2bf(v - bf2f(h));
        }
    }
    __syncthreads();

    // ---- phase 3 (MFMA, waves 0-3): g[16][64] = t @ Wb + bb + own
    if (wv < 4) {
        const int f0 = wv * 16;
        const float bias = ldf(bb, f0 + ln15, f32);
        f32x4 acc; acc[0] = bias; acc[1] = bias; acc[2] = bias; acc[3] = bias;
        #pragma unroll
        for (int s = 0; s < 4; s++) {
            Frag ah, al;
            ah.v = *(const s16x8*)&S.t.hi[ln15*PADT + s*32 + kg*8];
            al.v = *(const s16x8*)&S.t.lo[ln15*PADT + s*32 + kg*8];
            if (f32) {
                const float* W = (const float*)Wb;
                Frag bh, bl;
                loadB_f32(W + (s*32 + kg*8)*LAT + f0 + ln15, LAT, bh, bl);
                acc = MF(ah, bh, acc); acc = MF(al, bh, acc); acc = MF(ah, bl, acc);
            } else {
                const bf16* W = (const bf16*)Wb;
                Frag b;
                loadB_bf(W + (s*32 + kg*8)*LAT + f0 + ln15, LAT, b);
                acc = MF(ah, b, acc); acc = MF(al, b, acc);
            }
        }
        #pragma unroll
        for (int r = 0; r < 4; r++) {
            const int row = kg*4 + r, f = f0 + ln15, gi = base + row;
            const float o = acc[r] + S.own[row*LAT + f];
            if (!LAST) {
                st_coh(&hout[gi*LAT + f], o);
            } else {
                S.sh[row*PADH + f] = o;
                if (f32) ((float*)out)[gi*LAT + f] = o;     // output 0: final h
                else     ((bf16*)out)[gi*LAT + f] = f2bf(o);
            }
        }
    }
    __syncthreads();
}

__global__ __launch_bounds__(NTHR, 4) void k_fused(KArgs a)
{
    __shared__ Shm S;
    const int tid = threadIdx.x, blk = blockIdx.x;
    const int lane = tid & 63, wv = tid >> 6;
    const int ln15 = lane & 15, kg = lane >> 4;
    const int ev   = blk & (NEV - 1);
    const int slc  = blk >> 5;
    const int base = ev * NPE + slc * NPB;
    const int eb   = ev * NPE;

    // ---- P0: dtype detect (16 KB scan; wave shfl-reduce)
    {
        int c = 0;
        for (int i = tid; i < 4096; i += NTHR) {
            const u32 x = a.wdet[i];
            c += ((x >> 7)  & 0xffu) >= 0xC8u;
            c += ((x >> 23) & 0xffu) >= 0xC8u;
        }
        #pragma unroll
        for (int s = 32; s >= 1; s >>= 1) c += __shfl_xor(c, s, 64);
        if (lane == 0) S.u.red[wv] = c;
        __syncthreads();
        if (tid == 0) {
            int t = 0;
            #pragma unroll
            for (int i = 0; i < 8; i++) t += S.u.red[i];
            S.flag = (t > 64) ? 1 : 0;
        }
        __syncthreads();
    }
    const int f32 = S.flag;
    __syncthreads();

    // ---- P1: space_emb  h = leaky(x@W1+b1)@W2+b2
    {
        #pragma unroll
        for (int p = 0; p < 2; p++) {
            const int e = tid + p*NTHR, n = e >> 6, f = e & 63, node = base + n;
            float xr[4];
            if (f32) {
                const float4 x4 = ((const float4*)a.x)[node];
                xr[0] = x4.x; xr[1] = x4.y; xr[2] = x4.z; xr[3] = x4.w;
            } else {
                const ushort4 x4 = ((const ushort4*)a.x)[node];
                xr[0] = bf2f(x4.x); xr[1] = bf2f(x4.y);
                xr[2] = bf2f(x4.z); xr[3] = bf2f(x4.w);
            }
            float acc = ldf(a.bse1, f, f32);
            #pragma unroll
            for (int i = 0; i < 4; i++)
                acc = fmaf(xr[i], ldf(a.se1, i*LAT + f, f32), acc);
            acc = acc > 0.f ? acc : 0.01f*acc;              // leaky
            S.u.hid[n][f] = acc;
        }
        __syncthreads();
        // p2a (waves 0-3, MFMA): hA[16][64] = hid @ W2 + b2
        if (wv < 4) {
            const int f0 = wv * 16;
            const float bias = ldf(a.bse2, f0 + ln15, f32);
            f32x4 acc; acc[0] = bias; acc[1] = bias; acc[2] = bias; acc[3] = bias;
            Frag a0h, a0l, a1h, a1l;
            packA(&S.u.hid[ln15][ 0 + kg*8], a0h, a0l);
            packA(&S.u.hid[ln15][32 + kg*8], a1h, a1l);
            if (f32) {
                const float* W = (const float*)a.se2;
                Frag b0h, b0l, b1h, b1l;
                loadB_f32(W + ( 0 + kg*8)*LAT + f0 + ln15, LAT, b0h, b0l);
                loadB_f32(W + (32 + kg*8)*LAT + f0 + ln15, LAT, b1h, b1l);
                acc = MF(a0h, b0h, acc); acc = MF(a0l, b0h, acc); acc = MF(a0h, b0l, acc);
                acc = MF(a1h, b1h, acc); acc = MF(a1l, b1h, acc); acc = MF(a1h, b1l, acc);
            } else {
                const bf16* W = (const bf16*)a.se2;
                Frag b0, b1;
                loadB_bf(W + ( 0 + kg*8)*LAT + f0 + ln15, LAT, b0);
                loadB_bf(W + (32 + kg*8)*LAT + f0 + ln15, LAT, b1);
                acc = MF(a0h, b0, acc); acc = MF(a0l, b0, acc);
                acc = MF(a1h, b1, acc); acc = MF(a1l, b1, acc);
            }
            #pragma unroll
            for (int r = 0; r < 4; r++) {
                const int row = kg*4 + r;
                st_coh(&a.hA[(base + row)*LAT + f0 + ln15], acc[r]);
            }
        } else if (tid - 256 < 48) {
            // p2b: EXACT pos (3 cols) -- bit-identical fmaf chain (rounds 3-10)
            const int idx = tid - 256, n = idx / 3, f = idx % 3;
            float acc = ldf(a.bse2, f, f32);
            if (f32) {
                const float* W = (const float*)a.se2;
                #pragma unroll 8
                for (int j = 0; j < LAT; j++)
                    acc = fmaf(S.u.hid[n][j], W[j*LAT + f], acc);
            } else {
                const bf16* W = (const bf16*)a.se2;
                #pragma unroll 8
                for (int j = 0; j < LAT; j++)
                    acc = fmaf(S.u.hid[n][j], bf2f(W[j*LAT + f]), acc);
            }
            st_coh(&a.pos[(base + n)*3 + f], acc);
        }
    }
    eventbar(a.bar + (BARA_CNT + ev*128)/4, a.bar + (BARA_FLG + ev*128)/4);

    // ---- P2: kNN; 8 waves x 2 nodes, interleaved butterfly chains.
    u32 mypack;
    {
        for (int i = tid; i < NPE*3; i += NTHR) S.u.kp[i] = a.pos[(size_t)eb*3 + i];
        __syncthreads();
        const int n0 = base + wv*2, n1 = n0 + 1;
        const int nl0 = n0 - eb, nl1 = n1 - eb;
        const float px0 = S.u.kp[nl0*3], py0 = S.u.kp[nl0*3+1], pz0 = S.u.kp[nl0*3+2];
        const float px1 = S.u.kp[nl1*3], py1 = S.u.kp[nl1*3+1], pz1 = S.u.kp[nl1*3+2];
        u64 key0[4], key1[4];
        #pragma unroll
        for (int c = 0; c < 4; c++) {
            const int j = 64*c + lane;
            const float qx = S.u.kp[j*3], qy = S.u.kp[j*3+1], qz = S.u.kp[j*3+2];
            {
                const float dx = px0 - qx, dy = py0 - qy, dz = pz0 - qz;
                float dd = __fmul_rn(dx, dx);
                dd = __fadd_rn(dd, __fmul_rn(dy, dy));
                dd = __fadd_rn(dd, __fmul_rn(dz, dz));
                key0[c] = ((u64)__float_as_uint(dd) << 32) | (u32)j;
                if (j == nl0) key0[c] = ~0ull;
            }
            {
                const float dx = px1 - qx, dy = py1 - qy, dz = pz1 - qz;
                float dd = __fmul_rn(dx, dx);
                dd = __fadd_rn(dd, __fmul_rn(dy, dy));
                dd = __fadd_rn(dd, __fmul_rn(dz, dz));
                key1[c] = ((u64)__float_as_uint(dd) << 32) | (u32)j;
                if (j == nl1) key1[c] = ~0ull;
            }
        }
        #define CSWAP(K,A,B) { const u64 x_ = K[A], y_ = K[B]; \
                               K[A] = x_ < y_ ? x_ : y_; K[B] = x_ < y_ ? y_ : x_; }
        CSWAP(key0,0,1) CSWAP(key0,2,3) CSWAP(key0,0,2) CSWAP(key0,1,3) CSWAP(key0,1,2)
        CSWAP(key1,0,1) CSWAP(key1,2,3) CSWAP(key1,0,2) CSWAP(key1,1,3) CSWAP(key1,1,2)
        #undef CSWAP
        int myj0 = 0, myj1 = 0;
        #pragma unroll
        for (int k = 0; k < KNN; k++) {
            u64 m0 = key0[0], m1 = key1[0];
            #pragma unroll
            for (int s = 32; s >= 1; s >>= 1) {
                const u64 o0 = __shfl_xor(m0, s, 64);
                const u64 o1 = __shfl_xor(m1, s, 64);
                m0 = o0 < m0 ? o0 : m0;
                m1 = o1 < m1 ? o1 : m1;
            }
            if (lane == k) { myj0 = (int)(u32)m0; myj1 = (int)(u32)m1; }
            const bool h0 = (key0[0] == m0);
            key0[0] = h0 ? key0[1] : key0[0];
            key0[1] = h0 ? key0[2] : key0[1];
            key0[2] = h0 ? key0[3] : key0[2];
            key0[3] = h0 ? ~0ull   : key0[3];
            const bool h1 = (key1[0] == m1);
            key1[0] = h1 ? key1[1] : key1[0];
            key1[1] = h1 ? key1[2] : key1[1];
            key1[2] = h1 ? key1[3] : key1[2];
            key1[3] = h1 ? ~0ull   : key1[3];
        }
        mypack = (u32)myj0 | ((u32)myj1 << 16);
        if (lane < KNN) {
            const int gj0 = eb + myj0, gj1 = eb + myj1;
            if (f32) {
                float* o = (float*)a.out;
                o[EI0 + n0*KNN + lane]      = (float)gj0;   // output 2: ei
                o[EI0 + NK + n0*KNN + lane] = (float)n0;
                o[EI0 + n1*KNN + lane]      = (float)gj1;
                o[EI0 + NK + n1*KNN + lane] = (float)n1;
            } else {
                bf16* o = (bf16*)a.out;
                o[EI0 + n0*KNN + lane]      = f2bf((float)gj0);
                o[EI0 + NK + n0*KNN + lane] = f2bf((float)n0);
                o[EI0 + n1*KNN + lane]      = f2bf((float)gj1);
                o[EI0 + NK + n1*KNN + lane] = f2bf((float)n1);
            }
        }
        // no __syncthreads: each wave proceeds straight into its own gather
    }

    // ---- P3: GIN layer 1 (MFMA, hA -> hB)
    gin_layer<false>(S, base, eb, f32, mypack, a.hA, a.hB,
                     a.g1a, a.bg1a, a.g1b, a.bg1b, nullptr);
    eventbar(a.bar + (BARB_CNT + ev*128)/4, a.bar + (BARB_FLG + ev*128)/4);

    // ---- P4: GIN layer 2 (MFMA, hB -> sh + d_out h)
    gin_layer<true>(S, base, eb, f32, mypack, a.hB, nullptr,
                    a.g2a, a.bg2a, a.g2b, a.bg2b, a.out);

    // ---- P5: out_emb FFN
    {
        // p1 (waves 0-3, MFMA): st[16][64] = leaky(sh @ oe1 + boe1)
        if (wv < 4) {
            const int f0 = wv * 16;
            const float bias = ldf(a.boe1, f0 + ln15, f32);
            f32x4 acc; acc[0] = bias; acc[1] = bias; acc[2] = bias; acc[3] = bias;
            Frag a0h, a0l, a1h, a1l;
            packA(&S.sh[ln15*PADH +  0 + kg*8], a0h, a0l);
            packA(&S.sh[ln15*PADH + 32 + kg*8], a1h, a1l);
            if (f32) {
                const float* W = (const float*)a.oe1;
                Frag b0h, b0l, b1h, b1l;
                loadB_f32(W + ( 0 + kg*8)*LAT + f0 + ln15, LAT, b0h, b0l);
                loadB_f32(W + (32 + kg*8)*LAT + f0 + ln15, LAT, b1h, b1l);
                acc = MF(a0h, b0h, acc); acc = MF(a0l, b0h, acc); acc = MF(a0h, b0l, acc);
                acc = MF(a1h, b1h, acc); acc = MF(a1l, b1h, acc); acc = MF(a1h, b1l, acc);
            } else {
                const bf16* W = (const bf16*)a.oe1;
                Frag b0, b1;
                loadB_bf(W + ( 0 + kg*8)*LAT + f0 + ln15, LAT, b0);
                loadB_bf(W + (32 + kg*8)*LAT + f0 + ln15, LAT, b1);
                acc = MF(a0h, b0, acc); acc = MF(a0l, b0, acc);
                acc = MF(a1h, b1, acc); acc = MF(a1l, b1, acc);
            }
            #pragma unroll
            for (int r = 0; r < 4; r++) {
                const int row = kg*4 + r;
                float v = acc[r];
                v = v > 0.f ? v : 0.01f*v;                  // leaky
                S.u.st[row*LAT + f0 + ln15] = v;
            }
        }
        __syncthreads();
        // p2: x_emb = st @ oe2 + boe2 (64 dots of length 64)
        if (tid < NPB*4) {
            const int n = tid >> 2, ff = tid & 3;
            float acc;
            if (f32) {
                const float* W = (const float*)a.oe2;
                acc = ((const float*)a.boe2)[ff];
                for (int j = 0; j < LAT; j++)
                    acc = fmaf(S.u.st[n*LAT + j], W[j*4 + ff], acc);
            } else {
                const bf16* W = (const bf16*)a.oe2;
                acc = bf2f(((const bf16*)a.boe2)[ff]);
                for (int j = 0; j < LAT; j++)
                    acc = fmaf(S.u.st[n*LAT + j], bf2f(W[j*4 + ff]), acc);
            }
            const int xo = N_NODES*LAT + (base + n)*4 + ff; // output 1: x_emb
            if (f32) ((float*)a.out)[xo] = acc;
            else     ((bf16*)a.out)[xo] = f2bf(acc);
        }
    }
}

extern "C" void kernel_launch(void* const* d_in, const int* in_sizes, int n_in,
                              void* d_out, int out_size, void* d_ws, size_t ws_size,
                              hipStream_t stream)
{
    (void)in_sizes; (void)n_in; (void)out_size; (void)ws_size;
    char* ws = (char*)d_ws;

    KArgs a;
    a.x   = d_in[0];
    a.se1 = d_in[3];  a.bse1 = d_in[4];  a.se2 = d_in[5];  a.bse2 = d_in[6];
    a.g1a = d_in[7];  a.bg1a = d_in[8];  a.g1b = d_in[9];  a.bg1b = d_in[10];
    a.g2a = d_in[11]; a.bg2a = d_in[12]; a.g2b = d_in[13]; a.bg2b = d_in[14];
    a.oe1 = d_in[15]; a.boe1 = d_in[16]; a.oe2 = d_in[17]; a.boe2 = d_in[18];
    a.wdet = (const u32*)d_in[7];
    a.hA  = (float*)(ws + OFF_HA);
    a.hB  = (float*)(ws + OFF_HB);
    a.pos = (float*)(ws + OFF_POS);
    a.bar = (int*)ws;
    a.out = d_out;

    hipMemsetAsync(d_ws, 0, BAR_BYTES, stream);
    k_fused<<<dim3(NBLK), dim3(NTHR), 0, stream>>>(a);
}